// Round 9
// baseline (135.451 us; speedup 1.0000x reference)
//
#include <hip/hip_runtime.h>
#include <hip/hip_bf16.h>

#define B_SZ 4096
#define F_CAT 26
#define NUM_N 13
#define ED 64
#define D_DIM 1728   // 27*64
#define E_EXP 8
#define T_TASK 2
#define BOT0 512
#define BOT1 256
#define TOW0 128
#define TOW1 64

typedef __bf16 bf16x8 __attribute__((ext_vector_type(8)));
typedef float f32x4 __attribute__((ext_vector_type(4)));
typedef long lx2 __attribute__((ext_vector_type(2)));

__device__ __forceinline__ void gload_lds16(const void* g, void* l) {
  __builtin_amdgcn_global_load_lds(
      (const __attribute__((address_space(1))) void*)g,
      (__attribute__((address_space(3))) void*)l, 16, 0, 0);
}

#define BAR() do { asm volatile("" ::: "memory"); __builtin_amdgcn_s_barrier(); asm volatile("" ::: "memory"); } while (0)
#define VM6() asm volatile("s_waitcnt vmcnt(6)" ::: "memory")
#define VM4() asm volatile("s_waitcnt vmcnt(4)" ::: "memory")

// fp8 k-permutation within each 64-k block: one 16-B LDS read at slot lh
// yields both K=32 fragments: p = (k&7) + ((k>>3)&3)*16 + ((k>>5)&1)*8
__device__ __forceinline__ int permk(int k6) {
  return (k6 & 7) + (((k6 >> 3) & 3) << 4) + (((k6 >> 5) & 1) << 3);
}

// ---------------- f32 -> OCP e4m3fn (RNE, saturating) ----------------
__device__ __forceinline__ unsigned char f2e4m3(float x) {
  unsigned su = (__float_as_uint(x) >> 24) & 0x80u;
  float ax = fabsf(x);
  if (!(ax < 448.f)) return (unsigned char)(su | 0x7E);  // sat / NaN -> max
  if (ax == 0.f) return (unsigned char)su;
  int e;
  float m = frexpf(ax, &e);        // ax = m * 2^e, m in [0.5,1)
  int E = e - 1;                   // ax = (2m) * 2^E
  if (E < -6) {                    // subnormal: step 2^-9
    int mi = (int)rintf(ldexpf(ax, 9));
    if (mi >= 8) return (unsigned char)(su | 0x08);
    return (unsigned char)(su | mi);
  }
  int mi = (int)rintf(ldexpf(m, 4));  // [8,16]
  if (mi == 16) { mi = 8; E += 1; if (E > 8) return (unsigned char)(su | 0x7E); }
  return (unsigned char)(su | ((E + 7) << 3) | (mi - 8));
}

// ---------------- fused weight prep ----------------
__device__ __forceinline__ void trans_tile_bf16(
    const float* __restrict__ inp, __hip_bfloat16* __restrict__ outp,
    int R, int C, int cx, int ry, float (*tile)[33])
{
  int c0 = cx * 32, r0 = ry * 32;
  int tx = threadIdx.x & 31, ty = threadIdx.x >> 5; // 32 x 8
#pragma unroll
  for (int i = 0; i < 32; i += 8)
    tile[ty + i][tx] = inp[(size_t)(r0 + ty + i) * C + c0 + tx];
  __syncthreads();
#pragma unroll
  for (int i = 0; i < 32; i += 8)
    outp[(size_t)(c0 + ty + i) * R + r0 + tx] = __float2bfloat16(tile[tx][ty + i]);
}

__device__ __forceinline__ void trans_tile_fp8(
    const float* __restrict__ inp, unsigned char* __restrict__ outp,
    int R, int C, int cx, int ry, float (*tile)[33])
{
  int c0 = cx * 32, r0 = ry * 32;
  int tx = threadIdx.x & 31, ty = threadIdx.x >> 5;
#pragma unroll
  for (int i = 0; i < 32; i += 8)
    tile[ty + i][tx] = inp[(size_t)(r0 + ty + i) * C + c0 + tx];
  __syncthreads();
  int ki = r0 + tx;
  int outk = (ki & ~63) + permk(ki & 63);
#pragma unroll
  for (int i = 0; i < 32; i += 8)
    outp[(size_t)(c0 + ty + i) * R + outk] = f2e4m3(tile[tx][ty + i] * 16.f);
}

// We1 tiles: 6912 ; We2 tiles: 1024 ; Wg: 108 blocks
__global__ __launch_bounds__(256) void prep_weights(
    const float* __restrict__ We1, const float* __restrict__ We2,
    const float* __restrict__ Wg,
    unsigned char* __restrict__ We1T8, __hip_bfloat16* __restrict__ We2T,
    __hip_bfloat16* __restrict__ WgT)
{
  __shared__ float tile[32][33];
  int id = blockIdx.x;
  if (id < 6912) {
    int z = id / 864, r = id - z * 864;
    int cx = r & 15, ry = r >> 4;
    trans_tile_fp8(We1 + (size_t)z * D_DIM * BOT0, We1T8 + (size_t)z * D_DIM * BOT0,
                   D_DIM, BOT0, cx, ry, tile);
  } else if (id < 7936) {
    int r2 = id - 6912;
    int z = r2 >> 7, r = r2 & 127;
    int cx = r & 7, ry = r >> 3;
    trans_tile_bf16(We2 + (size_t)z * BOT0 * BOT1, We2T + (size_t)z * BOT0 * BOT1,
                    BOT0, BOT1, cx, ry, tile);
  } else {
    int i = (id - 7936) * 256 + threadIdx.x; // over 16*1728
    int n = i / D_DIM, d = i - n * D_DIM;
    int t = n >> 3, e2 = n & 7;
    WgT[i] = __float2bfloat16(Wg[((size_t)t * D_DIM + d) * E_EXP + e2]);
  }
}

// ---------------- embedding gather + numeric linear -> emb bf16 + emb8 fp8(x16, k-permuted)
__global__ __launch_bounds__(256) void embed_convert(
    const int* __restrict__ cat, const float* __restrict__ numx,
    const int* __restrict__ offsets, const float* __restrict__ W_emb,
    const float* __restrict__ Wn, const float* __restrict__ bnum,
    __hip_bfloat16* __restrict__ emb, unsigned char* __restrict__ emb8)
{
  const int UNITS = 27 * 16; // float4 units per row
  int b0 = blockIdx.x * 4;
  for (int idx = threadIdx.x; idx < 4 * UNITS; idx += 256) {
    int r = idx / UNITS, u = idx - r * UNITS;
    int f = u >> 4, d4 = (u & 15) * 4;
    int b = b0 + r;
    float4 v;
    if (f < F_CAT) {
      int row = cat[(size_t)b * F_CAT + f] + offsets[f];
      v = *reinterpret_cast<const float4*>(&W_emb[(size_t)row * ED + d4]);
    } else {
      float a0 = bnum[d4], a1 = bnum[d4 + 1], a2 = bnum[d4 + 2], a3 = bnum[d4 + 3];
#pragma unroll
      for (int n = 0; n < NUM_N; ++n) {
        float x = numx[(size_t)b * NUM_N + n];
        const float* wr = &Wn[n * ED + d4];
        a0 = fmaf(x, wr[0], a0);
        a1 = fmaf(x, wr[1], a1);
        a2 = fmaf(x, wr[2], a2);
        a3 = fmaf(x, wr[3], a3);
      }
      v = make_float4(a0, a1, a2, a3);
    }
    union { __hip_bfloat16 h[4]; uint2 u2; } pk;
    pk.h[0] = __float2bfloat16(v.x);
    pk.h[1] = __float2bfloat16(v.y);
    pk.h[2] = __float2bfloat16(v.z);
    pk.h[3] = __float2bfloat16(v.w);
    *reinterpret_cast<uint2*>(&emb[(size_t)b * D_DIM + f * ED + d4]) = pk.u2;
    union { unsigned char c[4]; unsigned int w; } p8;
    p8.c[0] = f2e4m3(v.x * 16.f);
    p8.c[1] = f2e4m3(v.y * 16.f);
    p8.c[2] = f2e4m3(v.z * 16.f);
    p8.c[3] = f2e4m3(v.w * 16.f);
    int pb = (d4 & 7) + (((d4 >> 3) & 3) << 4) + (((d4 >> 5) & 1) << 3);
    *reinterpret_cast<unsigned int*>(&emb8[(size_t)b * D_DIM + f * ED + pb]) = p8.w;
  }
}

// ---------------- gate GEMM (M=4096, N=16, K=1728) via MFMA + fused softmax
__global__ __launch_bounds__(256) void gate_mfma(
    const __hip_bfloat16* __restrict__ emb, const __hip_bfloat16* __restrict__ WgT,
    const float* __restrict__ bg, float* __restrict__ gate)
{
  int wid = threadIdx.x >> 6, lane = threadIdx.x & 63;
  int l15 = lane & 15, lh = lane >> 4;
  int r0 = (blockIdx.x * 4 + wid) * 16;
  f32x4 acc = {};
  const __hip_bfloat16* arow = emb + (size_t)(r0 + l15) * D_DIM + lh * 8;
  const __hip_bfloat16* brow = WgT + (size_t)l15 * D_DIM + lh * 8;
#pragma unroll 4
  for (int k = 0; k < D_DIM; k += 32) {
    bf16x8 af = *reinterpret_cast<const bf16x8*>(arow + k);
    bf16x8 bf = *reinterpret_cast<const bf16x8*>(brow + k);
    acc = __builtin_amdgcn_mfma_f32_16x16x32_bf16(af, bf, acc, 0, 0, 0);
  }
  int t = l15 >> 3, e = l15 & 7;
  float bv = bg[t * E_EXP + e];
#pragma unroll
  for (int r = 0; r < 4; ++r) {
    float lg = acc[r] + bv;
    float m = lg;
    m = fmaxf(m, __shfl_xor(m, 1));
    m = fmaxf(m, __shfl_xor(m, 2));
    m = fmaxf(m, __shfl_xor(m, 4));
    float ex = expf(lg - m);
    float s = ex;
    s += __shfl_xor(s, 1);
    s += __shfl_xor(s, 2);
    s += __shfl_xor(s, 4);
    int row = r0 + lh * 4 + r;
    gate[((size_t)t * B_SZ + row) * E_EXP + e] = ex / s;
  }
}

__device__ __forceinline__ void mfma16(const bf16x8* a, const bf16x8* b, f32x4 (*accRows)[4]) {
#pragma unroll
  for (int i = 0; i < 4; ++i)
#pragma unroll
    for (int j = 0; j < 4; ++j)
      accRows[i][j] = __builtin_amdgcn_mfma_f32_16x16x32_bf16(a[i], b[j], accRows[i][j], 0, 0, 0);
}

// =========================================================================
// FP8 4-phase 256x256 BK=64 GEMM (GEMM1). Round 9: per-tile work split into
// 4 phases of 16 MFMA with fine ds_read/gload/MFMA interleave (m196/m201
// evidence: fine interleave is the lever, coarse split hurts). Triple-
// buffered 16-KB A/B slabs; 1 gload/phase (4/tile) into buf (T+2)%3; one
// VM4 at ph3-end certifies T+1 (its 4 loads are the only older in-flight).
// Reads: ph0 va0(4)+vb(4), ph1 va1(4, one phase ahead of use), ph2/ph3: 0.
// =========================================================================
__global__ __launch_bounds__(512, 2) void gemm8p_fp8(
    const unsigned char* __restrict__ A8, size_t strideAe,
    const unsigned char* __restrict__ BT8,
    const float* __restrict__ bias,
    __hip_bfloat16* __restrict__ C,
    int M, int N, int K)
{
  extern __shared__ char smem[];
  int e = blockIdx.z;
  const unsigned char* Ap = A8 + strideAe * (size_t)e;
  const unsigned char* Bp = BT8 + (size_t)e * N * K;
  const float* bp = bias + (size_t)e * N;
  __hip_bfloat16* Cp = C + (size_t)e * M * N;
  int bm0 = blockIdx.x * 256, bn0 = blockIdx.y * 256;

  int tid = threadIdx.x;
  int wid = tid >> 6, lane = tid & 63;
  int l15 = lane & 15, lh = lane >> 4;
  int wrow = (wid >> 2) * 128, wcol = (wid & 3) * 64;

  // LDS read bases (proven bf16 swizzle geometry)
  int slotc = (lh ^ (((l15 >> 3) & 1) << 1)) << 4;
  const char* rdA = smem + (wrow + l15) * 64 + slotc;
  const char* rdB = smem + 49152 + (wcol + l15) * 64 + slotc;
  char* stA = smem + (wid << 10);
  char* stB = smem + 49152 + (wid << 10);

  // global staging: thread covers LDS bytes tid*16 of a 16-KB slab
  int srow = tid >> 2;                                   // 0..127
  int ssw = (tid & 3) ^ (((srow >> 3) & 1) << 1);        // pre-swizzled source slot
  const unsigned char* gA0 = Ap + (size_t)(bm0 + srow) * K + ssw * 16;
  const unsigned char* gA1 = Ap + (size_t)(bm0 + 128 + srow) * K + ssw * 16;
  const unsigned char* gB0 = Bp + (size_t)(bn0 + srow) * K + ssw * 16;
  const unsigned char* gB1 = Bp + (size_t)(bn0 + 128 + srow) * K + ssw * 16;

  f32x4 acc[8][4] = {};
  int NT = K >> 6;

  // prologue: T0 -> buf0, T1 -> buf1; VM4 certifies T0
  gload_lds16(gA0, stA);       gload_lds16(gA1, stA + 8192);
  gload_lds16(gB0, stB);       gload_lds16(gB1, stB + 8192);
  gload_lds16(gA0 + 64, stA + 16384); gload_lds16(gA1 + 64, stA + 16384 + 8192);
  gload_lds16(gB0 + 64, stB + 16384); gload_lds16(gB1 + 64, stB + 16384 + 8192);
  VM4();
  BAR();

  int bufc = 0, koff = 128;
  for (int T = 0; T < NT; ++T) {
    const char* As = rdA + bufc * 16384;
    const char* Bs = rdB + bufc * 16384;
    int sb16 = (bufc >= 1 ? bufc - 1 : 2) * 16384;   // (bufc+2)%3 slab base
    lx2 va0[4], va1[4], vb[4];

    // ---- ph0: read va0+vb; stage A0(T+2); MFMA kh0 rows 0..63
#pragma unroll
    for (int i = 0; i < 4; ++i) va0[i] = *(const lx2*)(As + i * 1024);
#pragma unroll
    for (int j = 0; j < 4; ++j) vb[j] = *(const lx2*)(Bs + j * 1024);
    gload_lds16(gA0 + koff, stA + sb16);
    BAR();
    __builtin_amdgcn_s_setprio(1);
#pragma unroll
    for (int i = 0; i < 4; ++i)
#pragma unroll
      for (int j = 0; j < 4; ++j)
        acc[i][j] = __builtin_amdgcn_mfma_f32_16x16x32_fp8_fp8(va0[i][0], vb[j][0], acc[i][j], 0, 0, 0);
    __builtin_amdgcn_s_setprio(0);
    BAR();

    // ---- ph1: read va1 (used next phase); stage A1(T+2); MFMA kh1 rows 0..63
#pragma unroll
    for (int i = 0; i < 4; ++i) va1[i] = *(const lx2*)(As + 4096 + i * 1024);
    gload_lds16(gA1 + koff, stA + sb16 + 8192);
    BAR();
    __builtin_amdgcn_s_setprio(1);
#pragma unroll
    for (int i = 0; i < 4; ++i)
#pragma unroll
      for (int j = 0; j < 4; ++j)
        acc[i][j] = __builtin_amdgcn_mfma_f32_16x16x32_fp8_fp8(va0[i][1], vb[j][1], acc[i][j], 0, 0, 0);
    __builtin_amdgcn_s_setprio(0);
    BAR();

    // ---- ph2: stage B0(T+2); MFMA kh0 rows 64..127
    gload_lds16(gB0 + koff, stB + sb16);
    BAR();
    __builtin_amdgcn_s_setprio(1);
#pragma unroll
    for (int i = 0; i < 4; ++i)
#pragma unroll
      for (int j = 0; j < 4; ++j)
        acc[4 + i][j] = __builtin_amdgcn_mfma_f32_16x16x32_fp8_fp8(va1[i][0], vb[j][0], acc[4 + i][j], 0, 0, 0);
    __builtin_amdgcn_s_setprio(0);
    BAR();

    // ---- ph3: stage B1(T+2); MFMA kh1 rows 64..127; VM4 certifies T+1
    gload_lds16(gB1 + koff, stB + sb16 + 8192);
    BAR();
    __builtin_amdgcn_s_setprio(1);
#pragma unroll
    for (int i = 0; i < 4; ++i)
#pragma unroll
      for (int j = 0; j < 4; ++j)
        acc[4 + i][j] = __builtin_amdgcn_mfma_f32_16x16x32_fp8_fp8(va1[i][1], vb[j][1], acc[4 + i][j], 0, 0, 0);
    __builtin_amdgcn_s_setprio(0);
    VM4();
    BAR();

    koff += 64;
    bufc = bufc == 2 ? 0 : bufc + 1;
  }

  // epilogue: drain tail prefetches (they land in LDS!), scale 1/256 + bias
  // + relu -> bf16 cs, then fully coalesced 16 B/lane stores.
  asm volatile("s_waitcnt vmcnt(0)" ::: "memory");
  BAR();
  __hip_bfloat16* cs = (__hip_bfloat16*)smem;
#pragma unroll
  for (int nj = 0; nj < 4; ++nj) {
    int col = wcol + nj * 16 + l15;
    float bv = bp[bn0 + col];
#pragma unroll
    for (int mi = 0; mi < 8; ++mi) {
      int rb = wrow + mi * 16 + lh * 4;
#pragma unroll
      for (int r = 0; r < 4; ++r) {
        float v = acc[mi][nj][r] * (1.f / 256.f) + bv;
        cs[(size_t)(rb + r) * 256 + col] = __float2bfloat16(fmaxf(v, 0.f));
      }
    }
  }
  BAR();
  {
    int rr = tid >> 5, c8 = (tid & 31) * 8;
#pragma unroll
    for (int p = 0; p < 16; ++p) {
      int row = p * 16 + rr;
      *reinterpret_cast<uint4*>(&Cp[(size_t)(bm0 + row) * N + bn0 + c8]) =
          *reinterpret_cast<const uint4*>(&cs[(size_t)row * 256 + c8]);
    }
  }
}

// =========================================================================
// bf16 BM=128 variant (gemm4p) for GEMM2 — unchanged (proven).
// =========================================================================
__global__ __launch_bounds__(512, 2) void gemm4p(
    const __hip_bfloat16* __restrict__ A, size_t strideAe,
    const __hip_bfloat16* __restrict__ BT,
    const float* __restrict__ bias,
    __hip_bfloat16* __restrict__ C,
    int M, int N, int K)
{
  extern __shared__ char smem[];
  int e = blockIdx.z;
  const __hip_bfloat16* Ap = A + strideAe * (size_t)e;
  const __hip_bfloat16* Bp = BT + (size_t)e * N * K;
  const float* bp = bias + (size_t)e * N;
  __hip_bfloat16* Cp = C + (size_t)e * M * N;
  int bm0 = blockIdx.x * 128, bn0 = blockIdx.y * 256;

  int tid = threadIdx.x;
  int wid = tid >> 6, lane = tid & 63;
  int l15 = lane & 15, lh = lane >> 4;
  int wrow = (wid >> 2) * 64, wcol = (wid & 3) * 64;

  int slotc = (lh ^ (((l15 >> 3) & 1) << 1)) << 4;
  const char* rdA = smem + (wrow + l15) * 64 + slotc;
  const char* rdB = smem + 32768 + (wcol + l15) * 64 + slotc;
  char* stA = smem + (wid << 10);
  char* stB = smem + 32768 + (wid << 10);

  const __hip_bfloat16* gA;
  const __hip_bfloat16* gB[2];
  {
    int X = (wid << 10) + (lane << 4);
    int row = X >> 6;
    int ss = ((X >> 4) & 3) ^ (((row >> 3) & 1) << 1);
    gA = Ap + (size_t)(bm0 + row) * K + ss * 8;
#pragma unroll
    for (int j = 0; j < 2; ++j) {
      int X2 = X + (j << 13);
      int row2 = X2 >> 6;
      int ss2 = ((X2 >> 4) & 3) ^ (((row2 >> 3) & 1) << 1);
      gB[j] = Bp + (size_t)(bn0 + row2) * K + ss2 * 8;
    }
  }

  f32x4 acc[4][4] = {};
  int NT = K >> 6;

  gload_lds16(gA, stA);
#pragma unroll
  for (int j = 0; j < 2; ++j) gload_lds16(gB[j], stB + (j << 13));
  gload_lds16(gA + 32, stA + 8192);
#pragma unroll
  for (int j = 0; j < 2; ++j) gload_lds16(gB[j] + 32, stB + 16384 + (j << 13));
  gload_lds16(gA + 64, stA + 16384);
#pragma unroll
  for (int j = 0; j < 2; ++j) gload_lds16(gB[j] + 64, stB + 32768 + (j << 13));
  VM6();
  BAR();

  for (int T = 0; T < NT; ++T) {
    int pA = (T & 1) << 14, qA = pA ^ 16384;
    int pB = (T & 1) << 15, qB = pB ^ 32768;
    const char* As = rdA + pA;
    const char* Bs = rdB + pB;
    bf16x8 a[4], b[4];

#pragma unroll
    for (int i = 0; i < 4; ++i) a[i] = *(const bf16x8*)(As + i * 1024);
#pragma unroll
    for (int j = 0; j < 4; ++j) b[j] = *(const bf16x8*)(Bs + j * 1024);
    gload_lds16(gA + 96, stA + qA + 8192);
#pragma unroll
    for (int j = 0; j < 2; ++j) gload_lds16(gB[j] + 96, stB + qB + 16384 + (j << 13));
    BAR();
    __builtin_amdgcn_s_setprio(1); mfma16(a, b, acc); __builtin_amdgcn_s_setprio(0);
    VM6();
    BAR();

#pragma unroll
    for (int i = 0; i < 4; ++i) a[i] = *(const bf16x8*)(As + 8192 + i * 1024);
#pragma unroll
    for (int j = 0; j < 4; ++j) b[j] = *(const bf16x8*)(Bs + 16384 + j * 1024);
    gload_lds16(gA + 128, stA + pA);
#pragma unroll
    for (int j = 0; j < 2; ++j) gload_lds16(gB[j] + 128, stB + pB + (j << 13));
    BAR();
    __builtin_amdgcn_s_setprio(1); mfma16(a, b, acc); __builtin_amdgcn_s_setprio(0);
    VM6();
    BAR();

    gA += 64;
#pragma unroll
    for (int j = 0; j < 2; ++j) gB[j] += 64;
  }

  asm volatile("s_waitcnt vmcnt(0)" ::: "memory");
  BAR();
  __hip_bfloat16* cs = (__hip_bfloat16*)smem;
#pragma unroll
  for (int nj = 0; nj < 4; ++nj) {
    int col = wcol + nj * 16 + l15;
    float bv = bp[bn0 + col];
#pragma unroll
    for (int mi = 0; mi < 4; ++mi) {
      int rb = wrow + mi * 16 + lh * 4;
#pragma unroll
      for (int r = 0; r < 4; ++r) {
        float v = acc[mi][nj][r] + bv;
        cs[(size_t)(rb + r) * 256 + col] = __float2bfloat16(fmaxf(v, 0.f));
      }
    }
  }
  BAR();
  {
    int rr = tid >> 5, c8 = (tid & 31) * 8;
#pragma unroll
    for (int p = 0; p < 8; ++p) {
      int row = p * 16 + rr;
      *reinterpret_cast<uint4*>(&Cp[(size_t)(bm0 + row) * N + bn0 + c8]) =
          *reinterpret_cast<const uint4*>(&cs[(size_t)row * 256 + c8]);
    }
  }
}

// ---------------- gate-combine + tower MLPs + sigmoid
// Round 9: ONE block per 16 batch rows computes BOTH tasks (fea read once).
#define TB 16
__global__ __launch_bounds__(256) void combine_tower(
    const float* __restrict__ gate, const __hip_bfloat16* __restrict__ fea,
    const float* __restrict__ Wt1, const float* __restrict__ bt1,
    const float* __restrict__ Wt2, const float* __restrict__ bt2,
    const float* __restrict__ Wt3, const float* __restrict__ bt3,
    float* __restrict__ out)
{
  int b0 = blockIdx.x * TB;
  int tid = threadIdx.x;
  __shared__ float gs[T_TASK][TB][E_EXP];
  __shared__ float tf[T_TASK][TB][BOT1];
  __shared__ float h1[T_TASK][TB][TOW0];
  __shared__ float h2[T_TASK][TB][TOW1];
  {
    // 2*16*8 = 256 = exactly one element per thread
    int t = tid >> 7, bl = (tid >> 3) & 15, e = tid & 7;
    gs[t][bl][e] = gate[((size_t)t * B_SZ + b0 + bl) * E_EXP + e];
  }
  __syncthreads();
  // task_fea for both tasks, fea read ONCE
  for (int i = tid; i < TB * BOT1; i += 256) {
    int bl = i >> 8, o = i & 255;
    float s0 = 0.f, s1 = 0.f;
#pragma unroll
    for (int e = 0; e < E_EXP; ++e) {
      float fv = __bfloat162float(fea[((size_t)e * B_SZ + b0 + bl) * BOT1 + o]);
      s0 = fmaf(gs[0][bl][e], fv, s0);
      s1 = fmaf(gs[1][bl][e], fv, s1);
    }
    tf[0][bl][o] = s0;
    tf[1][bl][o] = s1;
  }
  __syncthreads();
  // tower layer 1: 256 -> 128, both tasks (t = tid>>7)
  {
    int t = tid >> 7, h = tid & 127;
    float a[TB];
#pragma unroll
    for (int q = 0; q < TB; ++q) a[q] = 0.f;
    for (int d = 0; d < BOT1; ++d) {
      float w = Wt1[((size_t)t * BOT1 + d) * TOW0 + h];
#pragma unroll
      for (int q = 0; q < TB; ++q) a[q] = fmaf(w, tf[t][q][d], a[q]);
    }
    float bv = bt1[t * TOW0 + h];
#pragma unroll
    for (int q = 0; q < TB; ++q) h1[t][q][h] = fmaxf(a[q] + bv, 0.f);
  }
  __syncthreads();
  // tower layer 2: 128 -> 64, both tasks (t = tid>>7, half rows each)
  {
    int t = tid >> 7, hf = (tid >> 6) & 1, h = tid & 63;
    float a[8] = {0, 0, 0, 0, 0, 0, 0, 0};
    for (int d = 0; d < TOW0; ++d) {
      float w = Wt2[((size_t)t * TOW0 + d) * TOW1 + h];
#pragma unroll
      for (int q = 0; q < 8; ++q) a[q] = fmaf(w, h1[t][hf * 8 + q][d], a[q]);
    }
    float bv = bt2[t * TOW1 + h];
#pragma unroll
    for (int q = 0; q < 8; ++q) h2[t][hf * 8 + q][h] = fmaxf(a[q] + bv, 0.f);
  }
  __syncthreads();
  // tower layer 3: 64 -> 1 + sigmoid; 32 groups of 8 lanes
  {
    int g = tid >> 3, l8 = tid & 7;
    int t = g >> 4, bl = g & 15;
    float p = 0.f;
#pragma unroll
    for (int d = 0; d < TOW1 / 8; ++d)
      p = fmaf(h2[t][bl][l8 + d * 8], Wt3[t * TOW1 + l8 + d * 8], p);
    p += __shfl_down(p, 4, 8);
    p += __shfl_down(p, 2, 8);
    p += __shfl_down(p, 1, 8);
    if (l8 == 0) {
      float lg = p + bt3[t];
      out[(size_t)t * B_SZ + b0 + bl] = 1.f / (1.f + expf(-lg));
    }
  }
}

extern "C" void kernel_launch(void* const* d_in, const int* in_sizes, int n_in,
                              void* d_out, int out_size, void* d_ws, size_t ws_size,
                              hipStream_t stream) {
  const int* cat = (const int*)d_in[0];
  const float* numx = (const float*)d_in[1];
  const int* offsets = (const int*)d_in[2];
  const float* W_emb = (const float*)d_in[3];
  const float* Wn = (const float*)d_in[4];
  const float* bnv = (const float*)d_in[5];
  const float* We1 = (const float*)d_in[6];
  const float* be1 = (const float*)d_in[7];
  const float* We2 = (const float*)d_in[8];
  const float* be2 = (const float*)d_in[9];
  const float* Wg = (const float*)d_in[10];
  const float* bg = (const float*)d_in[11];
  const float* Wt1 = (const float*)d_in[12];
  const float* bt1 = (const float*)d_in[13];
  const float* Wt2 = (const float*)d_in[14];
  const float* bt2 = (const float*)d_in[15];
  const float* Wt3 = (const float*)d_in[16];
  const float* bt3 = (const float*)d_in[17];
  float* out = (float*)d_out;

  char* ws = (char*)d_ws;
  size_t off = 0;
  auto alloc = [&](size_t bytes) {
    char* p = ws + off;
    off += (bytes + 255) & ~(size_t)255;
    return p;
  };
  __hip_bfloat16* emb   = (__hip_bfloat16*)alloc((size_t)B_SZ * D_DIM * 2);
  unsigned char*  emb8  = (unsigned char*)alloc((size_t)B_SZ * D_DIM);
  unsigned char*  We1T8 = (unsigned char*)alloc((size_t)E_EXP * BOT0 * D_DIM);
  __hip_bfloat16* We2T  = (__hip_bfloat16*)alloc((size_t)E_EXP * BOT1 * BOT0 * 2);
  __hip_bfloat16* H     = (__hip_bfloat16*)alloc((size_t)E_EXP * B_SZ * BOT0 * 2);
  __hip_bfloat16* fea   = (__hip_bfloat16*)alloc((size_t)E_EXP * B_SZ * BOT1 * 2);
  float* gate = (float*)alloc((size_t)T_TASK * B_SZ * E_EXP * 4);
  __hip_bfloat16* WgT   = (__hip_bfloat16*)alloc((size_t)T_TASK * E_EXP * D_DIM * 2);
  (void)alloc(4096); // slack: gemm tail prefetch reads overrun up to ~256 B

  hipFuncSetAttribute((const void*)gemm8p_fp8,
                      hipFuncAttributeMaxDynamicSharedMemorySize, 131072);
  hipFuncSetAttribute((const void*)gemm4p,
                      hipFuncAttributeMaxDynamicSharedMemorySize, 98304);

  // 1. fused weight prep (We1T8 fp8 x16 k-permuted, We2T bf16, WgT bf16)
  prep_weights<<<dim3(8044), 256, 0, stream>>>(We1, We2, Wg, We1T8, We2T, WgT);

  // 2. embedding gather + numeric linear (bf16 emb for gate, fp8 x16 k-permuted emb8)
  embed_convert<<<dim3(B_SZ / 4), 256, 0, stream>>>(cat, numx, offsets, W_emb, Wn, bnv, emb, emb8);

  // 3. gate GEMM + softmax
  gate_mfma<<<dim3(B_SZ / 64), 256, 0, stream>>>(emb, WgT, bg, gate);

  // 4. expert layer 1 (fp8): (4096x1728)x(1728x512) x8 -> H bf16  [256 blocks]
  gemm8p_fp8<<<dim3(B_SZ / 256, BOT0 / 256, E_EXP), 512, 131072, stream>>>(
      emb8, (size_t)0, We1T8, be1, H, B_SZ, BOT0, D_DIM);

  // 5. expert layer 2 (bf16): (4096x512)x(512x256) x8 -> fea  [256 blocks]
  gemm4p<<<dim3(B_SZ / 128, BOT1 / 256, E_EXP), 512, 98304, stream>>>(
      H, (size_t)B_SZ * BOT0, We2T, be2, fea, B_SZ, BOT1, BOT0);

  // 6. gated combine + towers + sigmoid (both tasks per block; fea read once)
  combine_tower<<<dim3(B_SZ / TB), 256, 0, stream>>>(
      gate, fea, Wt1, bt1, Wt2, bt2, Wt3, bt3, out);
}

// Round 10
// 121.683 us; speedup vs baseline: 1.1131x; 1.1131x over previous
//
#include <hip/hip_runtime.h>
#include <hip/hip_bf16.h>

#define B_SZ 4096
#define F_CAT 26
#define NUM_N 13
#define ED 64
#define D_DIM 1728   // 27*64
#define E_EXP 8
#define T_TASK 2
#define BOT0 512
#define BOT1 256
#define TOW0 128
#define TOW1 64

typedef __bf16 bf16x8 __attribute__((ext_vector_type(8)));
typedef float f32x4 __attribute__((ext_vector_type(4)));
typedef long lx2 __attribute__((ext_vector_type(2)));

__device__ __forceinline__ void gload_lds16(const void* g, void* l) {
  __builtin_amdgcn_global_load_lds(
      (const __attribute__((address_space(1))) void*)g,
      (__attribute__((address_space(3))) void*)l, 16, 0, 0);
}

#define BAR() do { asm volatile("" ::: "memory"); __builtin_amdgcn_s_barrier(); asm volatile("" ::: "memory"); } while (0)
#define VM6() asm volatile("s_waitcnt vmcnt(6)" ::: "memory")
#define VM4() asm volatile("s_waitcnt vmcnt(4)" ::: "memory")

// fp8 k-permutation within each 64-k block: one 16-B LDS read at slot lh
// yields both K=32 fragments: p = (k&7) + ((k>>3)&3)*16 + ((k>>5)&1)*8
__device__ __forceinline__ int permk(int k6) {
  return (k6 & 7) + (((k6 >> 3) & 3) << 4) + (((k6 >> 5) & 1) << 3);
}

// ---------------- f32 -> OCP e4m3fn (RNE, saturating) ----------------
__device__ __forceinline__ unsigned char f2e4m3(float x) {
  unsigned su = (__float_as_uint(x) >> 24) & 0x80u;
  float ax = fabsf(x);
  if (!(ax < 448.f)) return (unsigned char)(su | 0x7E);  // sat / NaN -> max
  if (ax == 0.f) return (unsigned char)su;
  int e;
  float m = frexpf(ax, &e);        // ax = m * 2^e, m in [0.5,1)
  int E = e - 1;                   // ax = (2m) * 2^E
  if (E < -6) {                    // subnormal: step 2^-9
    int mi = (int)rintf(ldexpf(ax, 9));
    if (mi >= 8) return (unsigned char)(su | 0x08);
    return (unsigned char)(su | mi);
  }
  int mi = (int)rintf(ldexpf(m, 4));  // [8,16]
  if (mi == 16) { mi = 8; E += 1; if (E > 8) return (unsigned char)(su | 0x7E); }
  return (unsigned char)(su | ((E + 7) << 3) | (mi - 8));
}

// ---------------- fused weight prep ----------------
__device__ __forceinline__ void trans_tile_bf16(
    const float* __restrict__ inp, __hip_bfloat16* __restrict__ outp,
    int R, int C, int cx, int ry, float (*tile)[33])
{
  int c0 = cx * 32, r0 = ry * 32;
  int tx = threadIdx.x & 31, ty = threadIdx.x >> 5; // 32 x 8
#pragma unroll
  for (int i = 0; i < 32; i += 8)
    tile[ty + i][tx] = inp[(size_t)(r0 + ty + i) * C + c0 + tx];
  __syncthreads();
#pragma unroll
  for (int i = 0; i < 32; i += 8)
    outp[(size_t)(c0 + ty + i) * R + r0 + tx] = __float2bfloat16(tile[tx][ty + i]);
}

__device__ __forceinline__ void trans_tile_fp8(
    const float* __restrict__ inp, unsigned char* __restrict__ outp,
    int R, int C, int cx, int ry, float (*tile)[33])
{
  int c0 = cx * 32, r0 = ry * 32;
  int tx = threadIdx.x & 31, ty = threadIdx.x >> 5;
#pragma unroll
  for (int i = 0; i < 32; i += 8)
    tile[ty + i][tx] = inp[(size_t)(r0 + ty + i) * C + c0 + tx];
  __syncthreads();
  int ki = r0 + tx;
  int outk = (ki & ~63) + permk(ki & 63);
#pragma unroll
  for (int i = 0; i < 32; i += 8)
    outp[(size_t)(c0 + ty + i) * R + outk] = f2e4m3(tile[tx][ty + i] * 16.f);
}

// We1 tiles: 6912 ; We2 tiles: 1024 ; Wg: 108 blocks
__global__ __launch_bounds__(256) void prep_weights(
    const float* __restrict__ We1, const float* __restrict__ We2,
    const float* __restrict__ Wg,
    unsigned char* __restrict__ We1T8, __hip_bfloat16* __restrict__ We2T,
    unsigned char* __restrict__ WgT8)
{
  __shared__ float tile[32][33];
  int id = blockIdx.x;
  if (id < 6912) {
    int z = id / 864, r = id - z * 864;
    int cx = r & 15, ry = r >> 4;
    trans_tile_fp8(We1 + (size_t)z * D_DIM * BOT0, We1T8 + (size_t)z * D_DIM * BOT0,
                   D_DIM, BOT0, cx, ry, tile);
  } else if (id < 7936) {
    int r2 = id - 6912;
    int z = r2 >> 7, r = r2 & 127;
    int cx = r & 7, ry = r >> 3;
    trans_tile_bf16(We2 + (size_t)z * BOT0 * BOT1, We2T + (size_t)z * BOT0 * BOT1,
                    BOT0, BOT1, cx, ry, tile);
  } else {
    int i = (id - 7936) * 256 + threadIdx.x; // over 16*1728
    int n = i / D_DIM, d = i - n * D_DIM;
    int t = n >> 3, e2 = n & 7;
    int pd = (d & ~63) + permk(d & 63);
    WgT8[(size_t)n * D_DIM + pd] =
        f2e4m3(Wg[((size_t)t * D_DIM + d) * E_EXP + e2] * 16.f);
  }
}

// ---------------- embedding gather + numeric linear -> emb8 fp8(x16, k-permuted)
__global__ __launch_bounds__(256) void embed_convert(
    const int* __restrict__ cat, const float* __restrict__ numx,
    const int* __restrict__ offsets, const float* __restrict__ W_emb,
    const float* __restrict__ Wn, const float* __restrict__ bnum,
    unsigned char* __restrict__ emb8)
{
  const int UNITS = 27 * 16; // float4 units per row
  int b0 = blockIdx.x * 4;
  for (int idx = threadIdx.x; idx < 4 * UNITS; idx += 256) {
    int r = idx / UNITS, u = idx - r * UNITS;
    int f = u >> 4, d4 = (u & 15) * 4;
    int b = b0 + r;
    float4 v;
    if (f < F_CAT) {
      int row = cat[(size_t)b * F_CAT + f] + offsets[f];
      v = *reinterpret_cast<const float4*>(&W_emb[(size_t)row * ED + d4]);
    } else {
      float a0 = bnum[d4], a1 = bnum[d4 + 1], a2 = bnum[d4 + 2], a3 = bnum[d4 + 3];
#pragma unroll
      for (int n = 0; n < NUM_N; ++n) {
        float x = numx[(size_t)b * NUM_N + n];
        const float* wr = &Wn[n * ED + d4];
        a0 = fmaf(x, wr[0], a0);
        a1 = fmaf(x, wr[1], a1);
        a2 = fmaf(x, wr[2], a2);
        a3 = fmaf(x, wr[3], a3);
      }
      v = make_float4(a0, a1, a2, a3);
    }
    union { unsigned char c[4]; unsigned int w; } p8;
    p8.c[0] = f2e4m3(v.x * 16.f);
    p8.c[1] = f2e4m3(v.y * 16.f);
    p8.c[2] = f2e4m3(v.z * 16.f);
    p8.c[3] = f2e4m3(v.w * 16.f);
    int pb = (d4 & 7) + (((d4 >> 3) & 3) << 4) + (((d4 >> 5) & 1) << 3);
    *reinterpret_cast<unsigned int*>(&emb8[(size_t)b * D_DIM + f * ED + pb]) = p8.w;
  }
}

// ---------------- gate GEMM (M=4096, N=16, K=1728) in fp8 + fused softmax
// Reads the k-permuted fp8 buffers directly from global (no LDS): lane
// (l15,lh) reads 16 B at row*D + kb + lh*16 -> low 8 B = k(lh*8..+7),
// high 8 B = k(32+lh*8..+7)  [same derivation the passing GEMM1 uses].
__global__ __launch_bounds__(256) void gate_mfma(
    const unsigned char* __restrict__ emb8, const unsigned char* __restrict__ WgT8,
    const float* __restrict__ bg, float* __restrict__ gate)
{
  int wid = threadIdx.x >> 6, lane = threadIdx.x & 63;
  int l15 = lane & 15, lh = lane >> 4;
  int r0 = (blockIdx.x * 4 + wid) * 16;
  f32x4 acc = {};
  const unsigned char* arow = emb8 + (size_t)(r0 + l15) * D_DIM + lh * 16;
  const unsigned char* brow = WgT8 + (size_t)l15 * D_DIM + lh * 16;
#pragma unroll 3
  for (int k = 0; k < D_DIM; k += 64) {
    lx2 av = *reinterpret_cast<const lx2*>(arow + k);
    lx2 bv = *reinterpret_cast<const lx2*>(brow + k);
    acc = __builtin_amdgcn_mfma_f32_16x16x32_fp8_fp8(av[0], bv[0], acc, 0, 0, 0);
    acc = __builtin_amdgcn_mfma_f32_16x16x32_fp8_fp8(av[1], bv[1], acc, 0, 0, 0);
  }
  int t = l15 >> 3, e = l15 & 7;
  float bv = bg[t * E_EXP + e];
#pragma unroll
  for (int r = 0; r < 4; ++r) {
    float lg = acc[r] * (1.f / 256.f) + bv;
    float m = lg;
    m = fmaxf(m, __shfl_xor(m, 1));
    m = fmaxf(m, __shfl_xor(m, 2));
    m = fmaxf(m, __shfl_xor(m, 4));
    float ex = expf(lg - m);
    float s = ex;
    s += __shfl_xor(s, 1);
    s += __shfl_xor(s, 2);
    s += __shfl_xor(s, 4);
    int row = r0 + lh * 4 + r;
    gate[((size_t)t * B_SZ + row) * E_EXP + e] = ex / s;
  }
}

__device__ __forceinline__ void mfma16(const bf16x8* a, const bf16x8* b, f32x4 (*accRows)[4]) {
#pragma unroll
  for (int i = 0; i < 4; ++i)
#pragma unroll
    for (int j = 0; j < 4; ++j)
      accRows[i][j] = __builtin_amdgcn_mfma_f32_16x16x32_bf16(a[i], b[j], accRows[i][j], 0, 0, 0);
}

// =========================================================================
// FP8 2-phase 256x256 BK=64 GEMM (GEMM1) — ROUND-8 PROVEN VERSION (50.9 us).
// LDS geometry identical to the proven bf16 pattern; k-permuted global
// layout; triple-buffered 16-KB A/B slabs; 4 gloads at p0 into (buf+2)%3;
// one VM4 at p1-end certifies T+1. Operands x16; epilogue 1/256.
// =========================================================================
__global__ __launch_bounds__(512, 2) void gemm8p_fp8(
    const unsigned char* __restrict__ A8, size_t strideAe,
    const unsigned char* __restrict__ BT8,
    const float* __restrict__ bias,
    __hip_bfloat16* __restrict__ C,
    int M, int N, int K)
{
  extern __shared__ char smem[];
  int e = blockIdx.z;
  const unsigned char* Ap = A8 + strideAe * (size_t)e;
  const unsigned char* Bp = BT8 + (size_t)e * N * K;
  const float* bp = bias + (size_t)e * N;
  __hip_bfloat16* Cp = C + (size_t)e * M * N;
  int bm0 = blockIdx.x * 256, bn0 = blockIdx.y * 256;

  int tid = threadIdx.x;
  int wid = tid >> 6, lane = tid & 63;
  int l15 = lane & 15, lh = lane >> 4;
  int wrow = (wid >> 2) * 128, wcol = (wid & 3) * 64;

  int slotc = (lh ^ (((l15 >> 3) & 1) << 1)) << 4;
  const char* rdA = smem + (wrow + l15) * 64 + slotc;
  const char* rdB = smem + 49152 + (wcol + l15) * 64 + slotc;
  char* stA = smem + (wid << 10);
  char* stB = smem + 49152 + (wid << 10);

  int srow = tid >> 2;                                   // 0..127
  int ssw = (tid & 3) ^ (((srow >> 3) & 1) << 1);        // pre-swizzled source slot
  const unsigned char* gA0 = Ap + (size_t)(bm0 + srow) * K + ssw * 16;
  const unsigned char* gA1 = Ap + (size_t)(bm0 + 128 + srow) * K + ssw * 16;
  const unsigned char* gB0 = Bp + (size_t)(bn0 + srow) * K + ssw * 16;
  const unsigned char* gB1 = Bp + (size_t)(bn0 + 128 + srow) * K + ssw * 16;

  auto STAGE = [&](int koff, int buf) {
    gload_lds16(gA0 + koff, stA + buf * 16384);
    gload_lds16(gA1 + koff, stA + buf * 16384 + 8192);
    gload_lds16(gB0 + koff, stB + buf * 16384);
    gload_lds16(gB1 + koff, stB + buf * 16384 + 8192);
  };

  f32x4 acc[8][4] = {};
  int NT = K >> 6;

  // prologue: T0 -> buf0, T1 -> buf1; VM4 certifies T0
  STAGE(0, 0);
  STAGE(64, 1);
  VM4();
  BAR();

  int bufc = 0, koff = 128;
  for (int T = 0; T < NT; ++T) {
    const char* As = rdA + bufc * 16384;
    const char* Bs = rdB + bufc * 16384;
    int sb = bufc >= 1 ? bufc - 1 : 2;   // (bufc+2)%3
    lx2 va[4], vb[4];

    // ---- p0: rows wrow..+63, both K-halves; stage tile T+2
#pragma unroll
    for (int i = 0; i < 4; ++i) va[i] = *(const lx2*)(As + i * 1024);
#pragma unroll
    for (int j = 0; j < 4; ++j) vb[j] = *(const lx2*)(Bs + j * 1024);
    STAGE(koff, sb);
    BAR();
    __builtin_amdgcn_s_setprio(1);
#pragma unroll
    for (int i = 0; i < 4; ++i)
#pragma unroll
      for (int j = 0; j < 4; ++j)
        acc[i][j] = __builtin_amdgcn_mfma_f32_16x16x32_fp8_fp8(va[i][0], vb[j][0], acc[i][j], 0, 0, 0);
#pragma unroll
    for (int i = 0; i < 4; ++i)
#pragma unroll
      for (int j = 0; j < 4; ++j)
        acc[i][j] = __builtin_amdgcn_mfma_f32_16x16x32_fp8_fp8(va[i][1], vb[j][1], acc[i][j], 0, 0, 0);
    __builtin_amdgcn_s_setprio(0);
    BAR();

    // ---- p1: rows wrow+64..+127 (B frags reused); VM4 certifies T+1
#pragma unroll
    for (int i = 0; i < 4; ++i) va[i] = *(const lx2*)(As + 4096 + i * 1024);
    BAR();
    __builtin_amdgcn_s_setprio(1);
#pragma unroll
    for (int i = 0; i < 4; ++i)
#pragma unroll
      for (int j = 0; j < 4; ++j)
        acc[4 + i][j] = __builtin_amdgcn_mfma_f32_16x16x32_fp8_fp8(va[i][0], vb[j][0], acc[4 + i][j], 0, 0, 0);
#pragma unroll
    for (int i = 0; i < 4; ++i)
#pragma unroll
      for (int j = 0; j < 4; ++j)
        acc[4 + i][j] = __builtin_amdgcn_mfma_f32_16x16x32_fp8_fp8(va[i][1], vb[j][1], acc[4 + i][j], 0, 0, 0);
    __builtin_amdgcn_s_setprio(0);
    VM4();
    BAR();

    koff += 64;
    bufc = bufc == 2 ? 0 : bufc + 1;
  }

  // epilogue: drain tail prefetches (they land in LDS!), scale 1/256 + bias
  // + relu -> bf16 cs, then fully coalesced 16 B/lane stores.
  asm volatile("s_waitcnt vmcnt(0)" ::: "memory");
  BAR();
  __hip_bfloat16* cs = (__hip_bfloat16*)smem;
#pragma unroll
  for (int nj = 0; nj < 4; ++nj) {
    int col = wcol + nj * 16 + l15;
    float bv = bp[bn0 + col];
#pragma unroll
    for (int mi = 0; mi < 8; ++mi) {
      int rb = wrow + mi * 16 + lh * 4;
#pragma unroll
      for (int r = 0; r < 4; ++r) {
        float v = acc[mi][nj][r] * (1.f / 256.f) + bv;
        cs[(size_t)(rb + r) * 256 + col] = __float2bfloat16(fmaxf(v, 0.f));
      }
    }
  }
  BAR();
  {
    int rr = tid >> 5, c8 = (tid & 31) * 8;
#pragma unroll
    for (int p = 0; p < 16; ++p) {
      int row = p * 16 + rr;
      *reinterpret_cast<uint4*>(&Cp[(size_t)(bm0 + row) * N + bn0 + c8]) =
          *reinterpret_cast<const uint4*>(&cs[(size_t)row * 256 + c8]);
    }
  }
}

// =========================================================================
// bf16 BM=128 variant (gemm4p) for GEMM2 — unchanged (proven).
// =========================================================================
__global__ __launch_bounds__(512, 2) void gemm4p(
    const __hip_bfloat16* __restrict__ A, size_t strideAe,
    const __hip_bfloat16* __restrict__ BT,
    const float* __restrict__ bias,
    __hip_bfloat16* __restrict__ C,
    int M, int N, int K)
{
  extern __shared__ char smem[];
  int e = blockIdx.z;
  const __hip_bfloat16* Ap = A + strideAe * (size_t)e;
  const __hip_bfloat16* Bp = BT + (size_t)e * N * K;
  const float* bp = bias + (size_t)e * N;
  __hip_bfloat16* Cp = C + (size_t)e * M * N;
  int bm0 = blockIdx.x * 128, bn0 = blockIdx.y * 256;

  int tid = threadIdx.x;
  int wid = tid >> 6, lane = tid & 63;
  int l15 = lane & 15, lh = lane >> 4;
  int wrow = (wid >> 2) * 64, wcol = (wid & 3) * 64;

  int slotc = (lh ^ (((l15 >> 3) & 1) << 1)) << 4;
  const char* rdA = smem + (wrow + l15) * 64 + slotc;
  const char* rdB = smem + 32768 + (wcol + l15) * 64 + slotc;
  char* stA = smem + (wid << 10);
  char* stB = smem + 32768 + (wid << 10);

  const __hip_bfloat16* gA;
  const __hip_bfloat16* gB[2];
  {
    int X = (wid << 10) + (lane << 4);
    int row = X >> 6;
    int ss = ((X >> 4) & 3) ^ (((row >> 3) & 1) << 1);
    gA = Ap + (size_t)(bm0 + row) * K + ss * 8;
#pragma unroll
    for (int j = 0; j < 2; ++j) {
      int X2 = X + (j << 13);
      int row2 = X2 >> 6;
      int ss2 = ((X2 >> 4) & 3) ^ (((row2 >> 3) & 1) << 1);
      gB[j] = Bp + (size_t)(bn0 + row2) * K + ss2 * 8;
    }
  }

  f32x4 acc[4][4] = {};
  int NT = K >> 6;

  gload_lds16(gA, stA);
#pragma unroll
  for (int j = 0; j < 2; ++j) gload_lds16(gB[j], stB + (j << 13));
  gload_lds16(gA + 32, stA + 8192);
#pragma unroll
  for (int j = 0; j < 2; ++j) gload_lds16(gB[j] + 32, stB + 16384 + (j << 13));
  gload_lds16(gA + 64, stA + 16384);
#pragma unroll
  for (int j = 0; j < 2; ++j) gload_lds16(gB[j] + 64, stB + 32768 + (j << 13));
  VM6();
  BAR();

  for (int T = 0; T < NT; ++T) {
    int pA = (T & 1) << 14, qA = pA ^ 16384;
    int pB = (T & 1) << 15, qB = pB ^ 32768;
    const char* As = rdA + pA;
    const char* Bs = rdB + pB;
    bf16x8 a[4], b[4];

#pragma unroll
    for (int i = 0; i < 4; ++i) a[i] = *(const bf16x8*)(As + i * 1024);
#pragma unroll
    for (int j = 0; j < 4; ++j) b[j] = *(const bf16x8*)(Bs + j * 1024);
    gload_lds16(gA + 96, stA + qA + 8192);
#pragma unroll
    for (int j = 0; j < 2; ++j) gload_lds16(gB[j] + 96, stB + qB + 16384 + (j << 13));
    BAR();
    __builtin_amdgcn_s_setprio(1); mfma16(a, b, acc); __builtin_amdgcn_s_setprio(0);
    VM6();
    BAR();

#pragma unroll
    for (int i = 0; i < 4; ++i) a[i] = *(const bf16x8*)(As + 8192 + i * 1024);
#pragma unroll
    for (int j = 0; j < 4; ++j) b[j] = *(const bf16x8*)(Bs + 16384 + j * 1024);
    gload_lds16(gA + 128, stA + pA);
#pragma unroll
    for (int j = 0; j < 2; ++j) gload_lds16(gB[j] + 128, stB + pB + (j << 13));
    BAR();
    __builtin_amdgcn_s_setprio(1); mfma16(a, b, acc); __builtin_amdgcn_s_setprio(0);
    VM6();
    BAR();

    gA += 64;
#pragma unroll
    for (int j = 0; j < 2; ++j) gB[j] += 64;
  }

  asm volatile("s_waitcnt vmcnt(0)" ::: "memory");
  BAR();
  __hip_bfloat16* cs = (__hip_bfloat16*)smem;
#pragma unroll
  for (int nj = 0; nj < 4; ++nj) {
    int col = wcol + nj * 16 + l15;
    float bv = bp[bn0 + col];
#pragma unroll
    for (int mi = 0; mi < 4; ++mi) {
      int rb = wrow + mi * 16 + lh * 4;
#pragma unroll
      for (int r = 0; r < 4; ++r) {
        float v = acc[mi][nj][r] + bv;
        cs[(size_t)(rb + r) * 256 + col] = __float2bfloat16(fmaxf(v, 0.f));
      }
    }
  }
  BAR();
  {
    int rr = tid >> 5, c8 = (tid & 31) * 8;
#pragma unroll
    for (int p = 0; p < 8; ++p) {
      int row = p * 16 + rr;
      *reinterpret_cast<uint4*>(&Cp[(size_t)(bm0 + row) * N + bn0 + c8]) =
          *reinterpret_cast<const uint4*>(&cs[(size_t)row * 256 + c8]);
    }
  }
}

// ---------------- gate-combine + tower MLPs + sigmoid (ROUND-8 PROVEN)
#define TB 16
__global__ __launch_bounds__(256) void combine_tower(
    const float* __restrict__ gate, const __hip_bfloat16* __restrict__ fea,
    const float* __restrict__ Wt1, const float* __restrict__ bt1,
    const float* __restrict__ Wt2, const float* __restrict__ bt2,
    const float* __restrict__ Wt3, const float* __restrict__ bt3,
    float* __restrict__ out)
{
  int t = blockIdx.y;
  int b0 = blockIdx.x * TB;
  int tid = threadIdx.x;
  __shared__ float gs[TB][E_EXP];
  __shared__ float tf[TB][BOT1];
  __shared__ float h1[TB][TOW0];
  __shared__ float h2[TB][TOW1];
  if (tid < TB * E_EXP) {
    int bl = tid >> 3, e = tid & 7;
    gs[bl][e] = gate[((size_t)t * B_SZ + b0 + bl) * E_EXP + e];
  }
  __syncthreads();
  for (int i = tid; i < TB * BOT1; i += 256) {
    int bl = i >> 8, o = i & 255;
    float s = 0.f;
#pragma unroll
    for (int e = 0; e < E_EXP; ++e)
      s = fmaf(gs[bl][e], __bfloat162float(fea[((size_t)e * B_SZ + b0 + bl) * BOT1 + o]), s);
    tf[bl][o] = s;
  }
  __syncthreads();
  {
    int h = tid & 127, half = tid >> 7;
    float a[8] = {0, 0, 0, 0, 0, 0, 0, 0};
    for (int d = 0; d < BOT1; ++d) {
      float w = Wt1[((size_t)t * BOT1 + d) * TOW0 + h];
#pragma unroll
      for (int q = 0; q < 8; ++q) a[q] = fmaf(w, tf[half * 8 + q][d], a[q]);
    }
    float bv = bt1[t * TOW0 + h];
#pragma unroll
    for (int q = 0; q < 8; ++q) h1[half * 8 + q][h] = fmaxf(a[q] + bv, 0.f);
  }
  __syncthreads();
  {
    int h = tid & 63, qt = tid >> 6;
    float a[4] = {0, 0, 0, 0};
    for (int d = 0; d < TOW0; ++d) {
      float w = Wt2[((size_t)t * TOW0 + d) * TOW1 + h];
#pragma unroll
      for (int q = 0; q < 4; ++q) a[q] = fmaf(w, h1[qt * 4 + q][d], a[q]);
    }
    float bv = bt2[t * TOW1 + h];
#pragma unroll
    for (int q = 0; q < 4; ++q) h2[qt * 4 + q][h] = fmaxf(a[q] + bv, 0.f);
  }
  __syncthreads();
  {
    int l16 = tid & 15, bl = tid >> 4;
    float p = 0.f;
#pragma unroll
    for (int d = l16; d < TOW1; d += 16) p = fmaf(h2[bl][d], Wt3[t * TOW1 + d], p);
#pragma unroll
    for (int o = 8; o; o >>= 1) p += __shfl_down(p, o, 16);
    if (l16 == 0) {
      float lg = p + bt3[t];
      out[(size_t)t * B_SZ + b0 + bl] = 1.f / (1.f + expf(-lg));
    }
  }
}

extern "C" void kernel_launch(void* const* d_in, const int* in_sizes, int n_in,
                              void* d_out, int out_size, void* d_ws, size_t ws_size,
                              hipStream_t stream) {
  const int* cat = (const int*)d_in[0];
  const float* numx = (const float*)d_in[1];
  const int* offsets = (const int*)d_in[2];
  const float* W_emb = (const float*)d_in[3];
  const float* Wn = (const float*)d_in[4];
  const float* bnv = (const float*)d_in[5];
  const float* We1 = (const float*)d_in[6];
  const float* be1 = (const float*)d_in[7];
  const float* We2 = (const float*)d_in[8];
  const float* be2 = (const float*)d_in[9];
  const float* Wg = (const float*)d_in[10];
  const float* bg = (const float*)d_in[11];
  const float* Wt1 = (const float*)d_in[12];
  const float* bt1 = (const float*)d_in[13];
  const float* Wt2 = (const float*)d_in[14];
  const float* bt2 = (const float*)d_in[15];
  const float* Wt3 = (const float*)d_in[16];
  const float* bt3 = (const float*)d_in[17];
  float* out = (float*)d_out;

  char* ws = (char*)d_ws;
  size_t off = 0;
  auto alloc = [&](size_t bytes) {
    char* p = ws + off;
    off += (bytes + 255) & ~(size_t)255;
    return p;
  };
  unsigned char*  emb8  = (unsigned char*)alloc((size_t)B_SZ * D_DIM);
  unsigned char*  We1T8 = (unsigned char*)alloc((size_t)E_EXP * BOT0 * D_DIM);
  __hip_bfloat16* We2T  = (__hip_bfloat16*)alloc((size_t)E_EXP * BOT1 * BOT0 * 2);
  __hip_bfloat16* H     = (__hip_bfloat16*)alloc((size_t)E_EXP * B_SZ * BOT0 * 2);
  __hip_bfloat16* fea   = (__hip_bfloat16*)alloc((size_t)E_EXP * B_SZ * BOT1 * 2);
  float* gate = (float*)alloc((size_t)T_TASK * B_SZ * E_EXP * 4);
  unsigned char*  WgT8  = (unsigned char*)alloc((size_t)T_TASK * E_EXP * D_DIM);
  (void)alloc(4096); // slack: gemm tail prefetch reads overrun up to ~256 B

  hipFuncSetAttribute((const void*)gemm8p_fp8,
                      hipFuncAttributeMaxDynamicSharedMemorySize, 131072);
  hipFuncSetAttribute((const void*)gemm4p,
                      hipFuncAttributeMaxDynamicSharedMemorySize, 98304);

  // 1. fused weight prep (We1T8 fp8 x16 k-permuted, We2T bf16, WgT8 fp8 x16 k-permuted)
  prep_weights<<<dim3(8044), 256, 0, stream>>>(We1, We2, Wg, We1T8, We2T, WgT8);

  // 2. embedding gather + numeric linear -> emb8 only (fp8 x16, k-permuted)
  embed_convert<<<dim3(B_SZ / 4), 256, 0, stream>>>(cat, numx, offsets, W_emb, Wn, bnv, emb8);

  // 3. gate GEMM (fp8, direct-from-global) + softmax
  gate_mfma<<<dim3(B_SZ / 64), 256, 0, stream>>>(emb8, WgT8, bg, gate);

  // 4. expert layer 1 (fp8): (4096x1728)x(1728x512) x8 -> H bf16  [256 blocks]
  gemm8p_fp8<<<dim3(B_SZ / 256, BOT0 / 256, E_EXP), 512, 131072, stream>>>(
      emb8, (size_t)0, We1T8, be1, H, B_SZ, BOT0, D_DIM);

  // 5. expert layer 2 (bf16): (4096x512)x(512x256) x8 -> fea  [256 blocks]
  gemm4p<<<dim3(B_SZ / 128, BOT1 / 256, E_EXP), 512, 98304, stream>>>(
      H, (size_t)B_SZ * BOT0, We2T, be2, fea, B_SZ, BOT1, BOT0);

  // 6. gated combine + towers + sigmoid (round-8 proven split-task version)
  combine_tower<<<dim3(B_SZ / TB, T_TASK), 256, 0, stream>>>(
      gate, fea, Wt1, bt1, Wt2, bt2, Wt3, bt3, out);
}

// Round 11
// 117.694 us; speedup vs baseline: 1.1509x; 1.0339x over previous
//
#include <hip/hip_runtime.h>
#include <hip/hip_bf16.h>

#define B_SZ 4096
#define F_CAT 26
#define NUM_N 13
#define ED 64
#define D_DIM 1728   // 27*64
#define E_EXP 8
#define T_TASK 2
#define BOT0 512
#define BOT1 256
#define TOW0 128
#define TOW1 64

typedef __bf16 bf16x8 __attribute__((ext_vector_type(8)));
typedef float f32x4 __attribute__((ext_vector_type(4)));
typedef float f32x16 __attribute__((ext_vector_type(16)));
typedef long lx2 __attribute__((ext_vector_type(2)));
typedef int i32x4 __attribute__((ext_vector_type(4)));
typedef int i32x8 __attribute__((ext_vector_type(8)));

#define SCL 0x7F7F7F7F  // E8M0 1.0 in all 4 bytes

__device__ __forceinline__ void gload_lds16(const void* g, void* l) {
  __builtin_amdgcn_global_load_lds(
      (const __attribute__((address_space(1))) void*)g,
      (__attribute__((address_space(3))) void*)l, 16, 0, 0);
}

#define BAR() do { asm volatile("" ::: "memory"); __builtin_amdgcn_s_barrier(); asm volatile("" ::: "memory"); } while (0)
#define VM6() asm volatile("s_waitcnt vmcnt(6)" ::: "memory")
#define VM4() asm volatile("s_waitcnt vmcnt(4)" ::: "memory")

// old k-perm (16x16 frag layout) — still used for WgT8 (gate B operand)
__device__ __forceinline__ int permk(int k6) {
  return (k6 & 7) + (((k6 >> 3) & 3) << 4) + (((k6 >> 5) & 1) << 3);
}

// MX content layout (64-row regions): element (row, k_abs) -> byte position.
// Designed so the PROVEN staged-LDS read pattern delivers 32x32x64 fragments:
// lane (l15,lh) at chunk RB, piece p reads phys row (RB&~63)+(((RB>>5)&1)*2+p)*16+l15,
// unit lh, receiving A[RB + l15 + 16*(lh&1)][k: (lh>>1)*32 + p*16 ..+16).
__device__ __forceinline__ size_t mxpos(int row, int kabs, int K) {
  int kt = kabs >> 6, kk = kabs & 63;
  int reg = row & ~63, ro = row & 63;
  int sub = ro >> 5, rr = ro & 31, r = rr & 15;
  int u = ((kk >> 5) << 1) | ((rr >> 4) & 1);
  int p = (kk >> 4) & 1;
  int g = (sub << 1) | p;
  return (size_t)(reg + g * 16 + r) * K + kt * 64 + u * 16 + (kk & 15);
}

// ---------------- f32 -> OCP e4m3fn (RNE, saturating) ----------------
__device__ __forceinline__ unsigned char f2e4m3(float x) {
  unsigned su = (__float_as_uint(x) >> 24) & 0x80u;
  float ax = fabsf(x);
  if (!(ax < 448.f)) return (unsigned char)(su | 0x7E);
  if (ax == 0.f) return (unsigned char)su;
  int e;
  float m = frexpf(ax, &e);
  int E = e - 1;
  if (E < -6) {
    int mi = (int)rintf(ldexpf(ax, 9));
    if (mi >= 8) return (unsigned char)(su | 0x08);
    return (unsigned char)(su | mi);
  }
  int mi = (int)rintf(ldexpf(m, 4));
  if (mi == 16) { mi = 8; E += 1; if (E > 8) return (unsigned char)(su | 0x7E); }
  return (unsigned char)(su | ((E + 7) << 3) | (mi - 8));
}

// ---------------- fused weight prep ----------------
__device__ __forceinline__ void trans_tile_bf16(
    const float* __restrict__ inp, __hip_bfloat16* __restrict__ outp,
    int R, int C, int cx, int ry, float (*tile)[33])
{
  int c0 = cx * 32, r0 = ry * 32;
  int tx = threadIdx.x & 31, ty = threadIdx.x >> 5;
#pragma unroll
  for (int i = 0; i < 32; i += 8)
    tile[ty + i][tx] = inp[(size_t)(r0 + ty + i) * C + c0 + tx];
  __syncthreads();
#pragma unroll
  for (int i = 0; i < 32; i += 8)
    outp[(size_t)(c0 + ty + i) * R + r0 + tx] = __float2bfloat16(tile[tx][ty + i]);
}

// We1 transpose -> fp8 x16 in MX content layout
__device__ __forceinline__ void trans_tile_fp8mx(
    const float* __restrict__ inp, unsigned char* __restrict__ outp,
    int R, int C, int cx, int ry, float (*tile)[33])
{
  int c0 = cx * 32, r0 = ry * 32;
  int tx = threadIdx.x & 31, ty = threadIdx.x >> 5;
#pragma unroll
  for (int i = 0; i < 32; i += 8)
    tile[ty + i][tx] = inp[(size_t)(r0 + ty + i) * C + c0 + tx];
  __syncthreads();
  int ki = r0 + tx;
#pragma unroll
  for (int i = 0; i < 32; i += 8)
    outp[mxpos(c0 + ty + i, ki, R)] = f2e4m3(tile[tx][ty + i] * 16.f);
}

// We1 tiles: 6912 ; We2 tiles: 1024 ; Wg: 108 blocks
__global__ __launch_bounds__(256) void prep_weights(
    const float* __restrict__ We1, const float* __restrict__ We2,
    const float* __restrict__ Wg,
    unsigned char* __restrict__ We1T8, __hip_bfloat16* __restrict__ We2T,
    unsigned char* __restrict__ WgT8)
{
  __shared__ float tile[32][33];
  int id = blockIdx.x;
  if (id < 6912) {
    int z = id / 864, r = id - z * 864;
    int cx = r & 15, ry = r >> 4;
    trans_tile_fp8mx(We1 + (size_t)z * D_DIM * BOT0, We1T8 + (size_t)z * D_DIM * BOT0,
                     D_DIM, BOT0, cx, ry, tile);
  } else if (id < 7936) {
    int r2 = id - 6912;
    int z = r2 >> 7, r = r2 & 127;
    int cx = r & 7, ry = r >> 3;
    trans_tile_bf16(We2 + (size_t)z * BOT0 * BOT1, We2T + (size_t)z * BOT0 * BOT1,
                    BOT0, BOT1, cx, ry, tile);
  } else {
    int i = (id - 7936) * 256 + threadIdx.x; // over 16*1728
    int n = i / D_DIM, d = i - n * D_DIM;
    int t = n >> 3, e2 = n & 7;
    int pd = (d & ~63) + permk(d & 63);
    WgT8[(size_t)n * D_DIM + pd] =
        f2e4m3(Wg[((size_t)t * D_DIM + d) * E_EXP + e2] * 16.f);
  }
}

// ---------------- embedding gather + numeric linear -> emb8 (fp8 x16, MX layout)
// One thread per 16-B output unit; writes fully coalesced.
// units = 4096 rows * 108 units/row = 442368 -> grid 1728 x 256
__global__ __launch_bounds__(256) void embed_convert(
    const int* __restrict__ cat, const float* __restrict__ numx,
    const int* __restrict__ offsets, const float* __restrict__ W_emb,
    const float* __restrict__ Wn, const float* __restrict__ bnum,
    unsigned char* __restrict__ emb8)
{
  int W = blockIdx.x * 256 + threadIdx.x;
  int prow = W / 108, ucol = W - prow * 108;
  int f = ucol >> 2, u = ucol & 3;
  // invert MX map: phys (prow, unit u) -> (batch row b, k run start kk)
  int reg = prow & ~63, po = prow & 63;
  int g = po >> 4, r = po & 15;
  int sub = g >> 1, p = g & 1;
  int h = u >> 1, rbit = u & 1;
  int b = reg + sub * 32 + rbit * 16 + r;
  int kk = h * 32 + p * 16;
  float vals[16];
  if (f < F_CAT) {
    int row = cat[(size_t)b * F_CAT + f] + offsets[f];
    const float4* src = reinterpret_cast<const float4*>(&W_emb[(size_t)row * ED + kk]);
#pragma unroll
    for (int q = 0; q < 4; ++q) {
      float4 v = src[q];
      vals[q * 4 + 0] = v.x; vals[q * 4 + 1] = v.y;
      vals[q * 4 + 2] = v.z; vals[q * 4 + 3] = v.w;
    }
  } else {
#pragma unroll
    for (int j = 0; j < 16; ++j) vals[j] = bnum[kk + j];
    for (int n = 0; n < NUM_N; ++n) {
      float x = numx[(size_t)b * NUM_N + n];
      const float* wr = &Wn[n * ED + kk];
#pragma unroll
      for (int j = 0; j < 16; ++j) vals[j] = fmaf(x, wr[j], vals[j]);
    }
  }
  union { unsigned char c[16]; uint4 q; } o;
#pragma unroll
  for (int j = 0; j < 16; ++j) o.c[j] = f2e4m3(vals[j] * 16.f);
  *reinterpret_cast<uint4*>(&emb8[(size_t)prow * D_DIM + f * 64 + u * 16]) = o.q;
}

// ---------------- gate GEMM (fp8, M=4096,N=16,K=1728) + fused softmax
// A from MX-layout emb8 (two 8-B global loads per k-tile, per-lane addrs);
// B from WgT8 (old k-perm layout, 16-B lx2) — kappa maps match per half.
__global__ __launch_bounds__(256) void gate_mfma(
    const unsigned char* __restrict__ emb8, const unsigned char* __restrict__ WgT8,
    const float* __restrict__ bg, float* __restrict__ gate)
{
  int wid = threadIdx.x >> 6, lane = threadIdx.x & 63;
  int l15 = lane & 15, lh = lane >> 4;
  int r0 = (blockIdx.x * 4 + wid) * 16;
  f32x4 acc = {};
  int b = r0 + l15;
  int reg = b & ~63, ro = b & 63;
  int sub = ro >> 5, rr = ro & 31;
  int rbit = (rr >> 4) & 1, rq = rr & 15;
  int pgh = lh >> 1;
  int prow = reg + (((sub << 1) | pgh) << 4) + rq;
  const unsigned char* arow = emb8 + (size_t)prow * D_DIM + rbit * 16 + (lh & 1) * 8;
  const unsigned char* brow = WgT8 + (size_t)l15 * D_DIM + lh * 16;
#pragma unroll 3
  for (int k = 0; k < D_DIM; k += 64) {
    long a0 = *reinterpret_cast<const long*>(arow + k);
    long a1 = *reinterpret_cast<const long*>(arow + k + 32);
    lx2 bv = *reinterpret_cast<const lx2*>(brow + k);
    acc = __builtin_amdgcn_mfma_f32_16x16x32_fp8_fp8(a0, bv[0], acc, 0, 0, 0);
    acc = __builtin_amdgcn_mfma_f32_16x16x32_fp8_fp8(a1, bv[1], acc, 0, 0, 0);
  }
  int t = l15 >> 3, e = l15 & 7;
  float bv = bg[t * E_EXP + e];
#pragma unroll
  for (int r = 0; r < 4; ++r) {
    float lg = acc[r] * (1.f / 256.f) + bv;
    float m = lg;
    m = fmaxf(m, __shfl_xor(m, 1));
    m = fmaxf(m, __shfl_xor(m, 2));
    m = fmaxf(m, __shfl_xor(m, 4));
    float ex = expf(lg - m);
    float s = ex;
    s += __shfl_xor(s, 1);
    s += __shfl_xor(s, 2);
    s += __shfl_xor(s, 4);
    int row = r0 + lh * 4 + r;
    gate[((size_t)t * B_SZ + row) * E_EXP + e] = ex / s;
  }
}

__device__ __forceinline__ void mfma16(const bf16x8* a, const bf16x8* b, f32x4 (*accRows)[4]) {
#pragma unroll
  for (int i = 0; i < 4; ++i)
#pragma unroll
    for (int j = 0; j < 4; ++j)
      accRows[i][j] = __builtin_amdgcn_mfma_f32_16x16x32_bf16(a[i], b[j], accRows[i][j], 0, 0, 0);
}

// load a 32-B fragment (two b128 at +1024 = pieces p0,p1) into v8i32
__device__ __forceinline__ i32x8 ld32(const char* base, int off) {
  i32x4 a = *reinterpret_cast<const i32x4*>(base + off);
  i32x4 b = *reinterpret_cast<const i32x4*>(base + off + 1024);
  i32x8 r;
  r[0] = a[0]; r[1] = a[1]; r[2] = a[2]; r[3] = a[3];
  r[4] = b[0]; r[5] = b[1]; r[6] = b[2]; r[7] = b[3];
  return r;
}

// =========================================================================
// MX-fp8 2-phase 256x256 BK=64 GEMM (GEMM1): mfma_scale_f32_32x32x64_f8f6f4
// with unit scales (2x non-scaled fp8 rate). Staging/LDS/read pattern and
// schedule BYTE-IDENTICAL to the proven round-8 kernel; only the global
// CONTENT layout changed (mxpos) so the proven reads deliver 32x32 frags.
// Per wave: A = 4 x 32-row chunks (mi), B = 2 chunks (nj); 12 b128/tile.
// 8 MFMAs/tile/wave. acc = f32x16[4][2]. C/D: col=lane&31,
// row=(reg&3)+8*(reg>>2)+4*(lane>>5)  [m74/m101 verified].
// =========================================================================
__global__ __launch_bounds__(512, 2) void gemm_mx(
    const unsigned char* __restrict__ A8, size_t strideAe,
    const unsigned char* __restrict__ BT8,
    const float* __restrict__ bias,
    __hip_bfloat16* __restrict__ C,
    int M, int N, int K)
{
  extern __shared__ char smem[];
  int e = blockIdx.z;
  const unsigned char* Ap = A8 + strideAe * (size_t)e;
  const unsigned char* Bp = BT8 + (size_t)e * N * K;
  const float* bp = bias + (size_t)e * N;
  __hip_bfloat16* Cp = C + (size_t)e * M * N;
  int bm0 = blockIdx.x * 256, bn0 = blockIdx.y * 256;

  int tid = threadIdx.x;
  int wid = tid >> 6, lane = tid & 63;
  int l15 = lane & 15, lh = lane >> 4;
  int l31 = lane & 31, hl = lane >> 5;
  int wrow = (wid >> 2) * 128, wcol = (wid & 3) * 64;

  int slotc = (lh ^ (((l15 >> 3) & 1) << 1)) << 4;
  const char* rdA = smem + (wrow + l15) * 64 + slotc;
  const char* rdB = smem + 49152 + (wcol + l15) * 64 + slotc;
  char* stA = smem + (wid << 10);
  char* stB = smem + 49152 + (wid << 10);

  int srow = tid >> 2;
  int ssw = (tid & 3) ^ (((srow >> 3) & 1) << 1);
  const unsigned char* gA0 = Ap + (size_t)(bm0 + srow) * K + ssw * 16;
  const unsigned char* gA1 = Ap + (size_t)(bm0 + 128 + srow) * K + ssw * 16;
  const unsigned char* gB0 = Bp + (size_t)(bn0 + srow) * K + ssw * 16;
  const unsigned char* gB1 = Bp + (size_t)(bn0 + 128 + srow) * K + ssw * 16;

  auto STAGE = [&](int koff, int buf) {
    gload_lds16(gA0 + koff, stA + buf * 16384);
    gload_lds16(gA1 + koff, stA + buf * 16384 + 8192);
    gload_lds16(gB0 + koff, stB + buf * 16384);
    gload_lds16(gB1 + koff, stB + buf * 16384 + 8192);
  };

  f32x16 acc[4][2] = {};
  int NT = K >> 6;

  STAGE(0, 0);
  STAGE(64, 1);
  VM4();
  BAR();

  int bufc = 0, koff = 128;
  for (int T = 0; T < NT; ++T) {
    const char* As = rdA + bufc * 16384;
    const char* Bs = rdB + bufc * 16384;
    int sb = bufc >= 1 ? bufc - 1 : 2;   // (bufc+2)%3
    i32x8 va0, va1, vb0, vb1;

    // ---- p0: frags mi0,mi1 + both B chunks; stage tile T+2
    va0 = ld32(As, 0);
    va1 = ld32(As, 2048);
    vb0 = ld32(Bs, 0);
    vb1 = ld32(Bs, 2048);
    STAGE(koff, sb);
    BAR();
    __builtin_amdgcn_s_setprio(1);
    acc[0][0] = __builtin_amdgcn_mfma_scale_f32_32x32x64_f8f6f4(va0, vb0, acc[0][0], 0, 0, 0, SCL, 0, SCL);
    acc[0][1] = __builtin_amdgcn_mfma_scale_f32_32x32x64_f8f6f4(va0, vb1, acc[0][1], 0, 0, 0, SCL, 0, SCL);
    acc[1][0] = __builtin_amdgcn_mfma_scale_f32_32x32x64_f8f6f4(va1, vb0, acc[1][0], 0, 0, 0, SCL, 0, SCL);
    acc[1][1] = __builtin_amdgcn_mfma_scale_f32_32x32x64_f8f6f4(va1, vb1, acc[1][1], 0, 0, 0, SCL, 0, SCL);
    __builtin_amdgcn_s_setprio(0);
    BAR();

    // ---- p1: frags mi2,mi3; VM4 certifies T+1
    va0 = ld32(As, 4096);
    va1 = ld32(As, 4096 + 2048);
    BAR();
    __builtin_amdgcn_s_setprio(1);
    acc[2][0] = __builtin_amdgcn_mfma_scale_f32_32x32x64_f8f6f4(va0, vb0, acc[2][0], 0, 0, 0, SCL, 0, SCL);
    acc[2][1] = __builtin_amdgcn_mfma_scale_f32_32x32x64_f8f6f4(va0, vb1, acc[2][1], 0, 0, 0, SCL, 0, SCL);
    acc[3][0] = __builtin_amdgcn_mfma_scale_f32_32x32x64_f8f6f4(va1, vb0, acc[3][0], 0, 0, 0, SCL, 0, SCL);
    acc[3][1] = __builtin_amdgcn_mfma_scale_f32_32x32x64_f8f6f4(va1, vb1, acc[3][1], 0, 0, 0, SCL, 0, SCL);
    __builtin_amdgcn_s_setprio(0);
    VM4();
    BAR();

    koff += 64;
    bufc = bufc == 2 ? 0 : bufc + 1;
  }

  // epilogue: drain, scale 1/256 + bias + relu -> bf16 cs, coalesced stores
  asm volatile("s_waitcnt vmcnt(0)" ::: "memory");
  BAR();
  __hip_bfloat16* cs = (__hip_bfloat16*)smem;
#pragma unroll
  for (int mi = 0; mi < 4; ++mi) {
#pragma unroll
    for (int nj = 0; nj < 2; ++nj) {
      int colT = wcol + nj * 32 + l31;
      float bv = bp[bn0 + colT];
      f32x16 a = acc[mi][nj];
#pragma unroll
      for (int rg = 0; rg < 16; ++rg) {
        int rowT = wrow + mi * 32 + (rg & 3) + ((rg >> 2) << 3) + (hl << 2);
        float v = a[rg] * (1.f / 256.f) + bv;
        cs[(size_t)rowT * 256 + colT] = __float2bfloat16(fmaxf(v, 0.f));
      }
    }
  }
  BAR();
  {
    int rr = tid >> 5, c8 = (tid & 31) * 8;
#pragma unroll
    for (int p = 0; p < 16; ++p) {
      int row = p * 16 + rr;
      *reinterpret_cast<uint4*>(&Cp[(size_t)(bm0 + row) * N + bn0 + c8]) =
          *reinterpret_cast<const uint4*>(&cs[(size_t)row * 256 + c8]);
    }
  }
}

// =========================================================================
// bf16 BM=128 variant (gemm4p) for GEMM2 — unchanged (proven).
// =========================================================================
__global__ __launch_bounds__(512, 2) void gemm4p(
    const __hip_bfloat16* __restrict__ A, size_t strideAe,
    const __hip_bfloat16* __restrict__ BT,
    const float* __restrict__ bias,
    __hip_bfloat16* __restrict__ C,
    int M, int N, int K)
{
  extern __shared__ char smem[];
  int e = blockIdx.z;
  const __hip_bfloat16* Ap = A + strideAe * (size_t)e;
  const __hip_bfloat16* Bp = BT + (size_t)e * N * K;
  const float* bp = bias + (size_t)e * N;
  __hip_bfloat16* Cp = C + (size_t)e * M * N;
  int bm0 = blockIdx.x * 128, bn0 = blockIdx.y * 256;

  int tid = threadIdx.x;
  int wid = tid >> 6, lane = tid & 63;
  int l15 = lane & 15, lh = lane >> 4;
  int wrow = (wid >> 2) * 64, wcol = (wid & 3) * 64;

  int slotc = (lh ^ (((l15 >> 3) & 1) << 1)) << 4;
  const char* rdA = smem + (wrow + l15) * 64 + slotc;
  const char* rdB = smem + 32768 + (wcol + l15) * 64 + slotc;
  char* stA = smem + (wid << 10);
  char* stB = smem + 32768 + (wid << 10);

  const __hip_bfloat16* gA;
  const __hip_bfloat16* gB[2];
  {
    int X = (wid << 10) + (lane << 4);
    int row = X >> 6;
    int ss = ((X >> 4) & 3) ^ (((row >> 3) & 1) << 1);
    gA = Ap + (size_t)(bm0 + row) * K + ss * 8;
#pragma unroll
    for (int j = 0; j < 2; ++j) {
      int X2 = X + (j << 13);
      int row2 = X2 >> 6;
      int ss2 = ((X2 >> 4) & 3) ^ (((row2 >> 3) & 1) << 1);
      gB[j] = Bp + (size_t)(bn0 + row2) * K + ss2 * 8;
    }
  }

  f32x4 acc[4][4] = {};
  int NT = K >> 6;

  gload_lds16(gA, stA);
#pragma unroll
  for (int j = 0; j < 2; ++j) gload_lds16(gB[j], stB + (j << 13));
  gload_lds16(gA + 32, stA + 8192);
#pragma unroll
  for (int j = 0; j < 2; ++j) gload_lds16(gB[j] + 32, stB + 16384 + (j << 13));
  gload_lds16(gA + 64, stA + 16384);
#pragma unroll
  for (int j = 0; j < 2; ++j) gload_lds16(gB[j] + 64, stB + 32768 + (j << 13));
  VM6();
  BAR();

  for (int T = 0; T < NT; ++T) {
    int pA = (T & 1) << 14, qA = pA ^ 16384;
    int pB = (T & 1) << 15, qB = pB ^ 32768;
    const char* As = rdA + pA;
    const char* Bs = rdB + pB;
    bf16x8 a[4], b[4];

#pragma unroll
    for (int i = 0; i < 4; ++i) a[i] = *(const bf16x8*)(As + i * 1024);
#pragma unroll
    for (int j = 0; j < 4; ++j) b[j] = *(const bf16x8*)(Bs + j * 1024);
    gload_lds16(gA + 96, stA + qA + 8192);
#pragma unroll
    for (int j = 0; j < 2; ++j) gload_lds16(gB[j] + 96, stB + qB + 16384 + (j << 13));
    BAR();
    __builtin_amdgcn_s_setprio(1); mfma16(a, b, acc); __builtin_amdgcn_s_setprio(0);
    VM6();
    BAR();

#pragma unroll
    for (int i = 0; i < 4; ++i) a[i] = *(const bf16x8*)(As + 8192 + i * 1024);
#pragma unroll
    for (int j = 0; j < 4; ++j) b[j] = *(const bf16x8*)(Bs + 16384 + j * 1024);
    gload_lds16(gA + 128, stA + pA);
#pragma unroll
    for (int j = 0; j < 2; ++j) gload_lds16(gB[j] + 128, stB + pB + (j << 13));
    BAR();
    __builtin_amdgcn_s_setprio(1); mfma16(a, b, acc); __builtin_amdgcn_s_setprio(0);
    VM6();
    BAR();

    gA += 64;
#pragma unroll
    for (int j = 0; j < 2; ++j) gB[j] += 64;
  }

  asm volatile("s_waitcnt vmcnt(0)" ::: "memory");
  BAR();
  __hip_bfloat16* cs = (__hip_bfloat16*)smem;
#pragma unroll
  for (int nj = 0; nj < 4; ++nj) {
    int col = wcol + nj * 16 + l15;
    float bv = bp[bn0 + col];
#pragma unroll
    for (int mi = 0; mi < 4; ++mi) {
      int rb = wrow + mi * 16 + lh * 4;
#pragma unroll
      for (int r = 0; r < 4; ++r) {
        float v = acc[mi][nj][r] + bv;
        cs[(size_t)(rb + r) * 256 + col] = __float2bfloat16(fmaxf(v, 0.f));
      }
    }
  }
  BAR();
  {
    int rr = tid >> 5, c8 = (tid & 31) * 8;
#pragma unroll
    for (int p = 0; p < 8; ++p) {
      int row = p * 16 + rr;
      *reinterpret_cast<uint4*>(&Cp[(size_t)(bm0 + row) * N + bn0 + c8]) =
          *reinterpret_cast<const uint4*>(&cs[(size_t)row * 256 + c8]);
    }
  }
}

// ---------------- gate-combine + tower MLPs + sigmoid (proven)
#define TB 16
__global__ __launch_bounds__(256) void combine_tower(
    const float* __restrict__ gate, const __hip_bfloat16* __restrict__ fea,
    const float* __restrict__ Wt1, const float* __restrict__ bt1,
    const float* __restrict__ Wt2, const float* __restrict__ bt2,
    const float* __restrict__ Wt3, const float* __restrict__ bt3,
    float* __restrict__ out)
{
  int t = blockIdx.y;
  int b0 = blockIdx.x * TB;
  int tid = threadIdx.x;
  __shared__ float gs[TB][E_EXP];
  __shared__ float tf[TB][BOT1];
  __shared__ float h1[TB][TOW0];
  __shared__ float h2[TB][TOW1];
  if (tid < TB * E_EXP) {
    int bl = tid >> 3, e = tid & 7;
    gs[bl][e] = gate[((size_t)t * B_SZ + b0 + bl) * E_EXP + e];
  }
  __syncthreads();
  for (int i = tid; i < TB * BOT1; i += 256) {
    int bl = i >> 8, o = i & 255;
    float s = 0.f;
#pragma unroll
    for (int e = 0; e < E_EXP; ++e)
      s = fmaf(gs[bl][e], __bfloat162float(fea[((size_t)e * B_SZ + b0 + bl) * BOT1 + o]), s);
    tf[bl][o] = s;
  }
  __syncthreads();
  {
    int h = tid & 127, half = tid >> 7;
    float a[8] = {0, 0, 0, 0, 0, 0, 0, 0};
    for (int d = 0; d < BOT1; ++d) {
      float w = Wt1[((size_t)t * BOT1 + d) * TOW0 + h];
#pragma unroll
      for (int q = 0; q < 8; ++q) a[q] = fmaf(w, tf[half * 8 + q][d], a[q]);
    }
    float bv = bt1[t * TOW0 + h];
#pragma unroll
    for (int q = 0; q < 8; ++q) h1[half * 8 + q][h] = fmaxf(a[q] + bv, 0.f);
  }
  __syncthreads();
  {
    int h = tid & 63, qt = tid >> 6;
    float a[4] = {0, 0, 0, 0};
    for (int d = 0; d < TOW0; ++d) {
      float w = Wt2[((size_t)t * TOW0 + d) * TOW1 + h];
#pragma unroll
      for (int q = 0; q < 4; ++q) a[q] = fmaf(w, h1[qt * 4 + q][d], a[q]);
    }
    float bv = bt2[t * TOW1 + h];
#pragma unroll
    for (int q = 0; q < 4; ++q) h2[qt * 4 + q][h] = fmaxf(a[q] + bv, 0.f);
  }
  __syncthreads();
  {
    int l16 = tid & 15, bl = tid >> 4;
    float p = 0.f;
#pragma unroll
    for (int d = l16; d < TOW1; d += 16) p = fmaf(h2[bl][d], Wt3[t * TOW1 + d], p);
#pragma unroll
    for (int o = 8; o; o >>= 1) p += __shfl_down(p, o, 16);
    if (l16 == 0) {
      float lg = p + bt3[t];
      out[(size_t)t * B_SZ + b0 + bl] = 1.f / (1.f + expf(-lg));
    }
  }
}

extern "C" void kernel_launch(void* const* d_in, const int* in_sizes, int n_in,
                              void* d_out, int out_size, void* d_ws, size_t ws_size,
                              hipStream_t stream) {
  const int* cat = (const int*)d_in[0];
  const float* numx = (const float*)d_in[1];
  const int* offsets = (const int*)d_in[2];
  const float* W_emb = (const float*)d_in[3];
  const float* Wn = (const float*)d_in[4];
  const float* bnv = (const float*)d_in[5];
  const float* We1 = (const float*)d_in[6];
  const float* be1 = (const float*)d_in[7];
  const float* We2 = (const float*)d_in[8];
  const float* be2 = (const float*)d_in[9];
  const float* Wg = (const float*)d_in[10];
  const float* bg = (const float*)d_in[11];
  const float* Wt1 = (const float*)d_in[12];
  const float* bt1 = (const float*)d_in[13];
  const float* Wt2 = (const float*)d_in[14];
  const float* bt2 = (const float*)d_in[15];
  const float* Wt3 = (const float*)d_in[16];
  const float* bt3 = (const float*)d_in[17];
  float* out = (float*)d_out;

  char* ws = (char*)d_ws;
  size_t off = 0;
  auto alloc = [&](size_t bytes) {
    char* p = ws + off;
    off += (bytes + 255) & ~(size_t)255;
    return p;
  };
  unsigned char*  emb8  = (unsigned char*)alloc((size_t)B_SZ * D_DIM);
  unsigned char*  We1T8 = (unsigned char*)alloc((size_t)E_EXP * BOT0 * D_DIM);
  __hip_bfloat16* We2T  = (__hip_bfloat16*)alloc((size_t)E_EXP * BOT1 * BOT0 * 2);
  __hip_bfloat16* H     = (__hip_bfloat16*)alloc((size_t)E_EXP * B_SZ * BOT0 * 2);
  __hip_bfloat16* fea   = (__hip_bfloat16*)alloc((size_t)E_EXP * B_SZ * BOT1 * 2);
  float* gate = (float*)alloc((size_t)T_TASK * B_SZ * E_EXP * 4);
  unsigned char*  WgT8  = (unsigned char*)alloc((size_t)T_TASK * E_EXP * D_DIM);
  (void)alloc(4096); // slack: gemm tail prefetch reads overrun up to ~256 B

  hipFuncSetAttribute((const void*)gemm_mx,
                      hipFuncAttributeMaxDynamicSharedMemorySize, 131072);
  hipFuncSetAttribute((const void*)gemm4p,
                      hipFuncAttributeMaxDynamicSharedMemorySize, 98304);

  // 1. weight prep (We1T8 fp8 x16 MX layout, We2T bf16, WgT8 fp8 x16 k-perm)
  prep_weights<<<dim3(8044), 256, 0, stream>>>(We1, We2, Wg, We1T8, We2T, WgT8);

  // 2. embedding gather + numeric linear -> emb8 (fp8 x16, MX layout, coalesced)
  embed_convert<<<dim3(B_SZ * 108 / 256), 256, 0, stream>>>(
      cat, numx, offsets, W_emb, Wn, bnv, emb8);

  // 3. gate GEMM (fp8 direct-from-global) + softmax
  gate_mfma<<<dim3(B_SZ / 64), 256, 0, stream>>>(emb8, WgT8, bg, gate);

  // 4. expert layer 1 (MX-fp8 32x32x64): (4096x1728)x(1728x512) x8 -> H bf16
  gemm_mx<<<dim3(B_SZ / 256, BOT0 / 256, E_EXP), 512, 131072, stream>>>(
      emb8, (size_t)0, We1T8, be1, H, B_SZ, BOT0, D_DIM);

  // 5. expert layer 2 (bf16): (4096x512)x(512x256) x8 -> fea
  gemm4p<<<dim3(B_SZ / 128, BOT1 / 256, E_EXP), 512, 98304, stream>>>(
      H, (size_t)B_SZ * BOT0, We2T, be2, fea, B_SZ, BOT1, BOT0);

  // 6. gated combine + towers + sigmoid
  combine_tower<<<dim3(B_SZ / TB, T_TASK), 256, 0, stream>>>(
      gate, fea, Wt1, bt1, Wt2, bt2, Wt3, bt3, out);
}